// Round 7
// baseline (659.095 us; speedup 1.0000x reference)
//
#include <hip/hip_runtime.h>
#include <hip/hip_bf16.h>
#include <stdint.h>

// DRNN_75204877353433: windowed bidirectional GRU (W=15) + BN + MLP + masked maxpool + linear
// B=32 S=512 W=15 E=300 H=256 V=50000 C=2, G=3H=768

typedef unsigned short u16;
typedef unsigned int u32;
typedef float f32x16 __attribute__((ext_vector_type(16)));
typedef float f32x4  __attribute__((ext_vector_type(4)));
typedef short bf16x8 __attribute__((ext_vector_type(8)));

#define MFMA32 __builtin_amdgcn_mfma_f32_32x32x16_bf16
#define MFMA16 __builtin_amdgcn_mfma_f32_16x16x32_bf16

#define NB 32
#define NS 512
#define NW 15
#define NE 300
#define NH 256
#define NG 768
#define NCELL (NB*NS)   // 16384
#define EPAD 320        // E padded to multiple of 16
#define MRE 32          // rows per block in eproj/mlp
#define MRR 64          // rows per block in recur
#define HS 264          // h_lds row stride (u16)
#define WROWS 78        // xproj window rows per block (64 + 14)
#define RZS 260         // rz_lds row stride (u32)

__device__ __forceinline__ float bf2f(u16 u){
    union { unsigned int i; float f; } v; v.i = ((unsigned int)u) << 16; return v.f;
}
__device__ __forceinline__ u16 f2bf(float f){
    union { float f; unsigned int i; } v; v.f = f;
    unsigned int x = v.i;
    x += 0x7fffu + ((x >> 16) & 1u);   // RNE
    return (u16)(x >> 16);
}
__device__ __forceinline__ u16 f2bf_rh(float f){   // round-half-up, 2 VALU ops
    return (u16)((__float_as_uint(f) + 0x8000u) >> 16);
}
__device__ __forceinline__ unsigned fkey(float f){   // order-preserving float->uint map
    unsigned b = __float_as_uint(f);
    return b ^ ((b & 0x80000000u) ? 0xFFFFFFFFu : 0x80000000u);
}

// ---- hw transcendental gate math (validated round 1): short chains, saturating edges ----
__device__ __forceinline__ float sigm_hw(float x){   // 1/(1+2^(-x*log2e))
    return __builtin_amdgcn_rcpf(1.0f + __builtin_amdgcn_exp2f(x * -1.44269504f));
}
__device__ __forceinline__ float tanh_hw(float x){   // 1 - 2/(1+2^(2x*log2e))
    return fmaf(-2.0f, __builtin_amdgcn_rcpf(1.0f + __builtin_amdgcn_exp2f(x * 2.88539008f)), 1.0f);
}

// ---------------- prep ----------------
// ALL MFMA B-operands fragment-packed: per (plane, wave, kc) a contiguous 1KB block,
// element addr = base + lane*16B -> coalesced dwordx4 loads everywhere.
__global__ void prep_kernel(const float* __restrict__ Wih_f, const float* __restrict__ Wih_b,
                            const float* __restrict__ Whh_f, const float* __restrict__ Whh_b,
                            const float* __restrict__ mlpW,
                            u16* __restrict__ WihF_p, u16* __restrict__ WihB_p,
                            u16* __restrict__ WhhF_p, u16* __restrict__ WhhB_p,
                            u16* __restrict__ mlpW_p,
                            float* __restrict__ bnSum, float* __restrict__ bnSumSq,
                            unsigned* __restrict__ pooled_u)
{
    const int tid  = blockIdx.x*blockDim.x + threadIdx.x;
    const int nthr = gridDim.x*blockDim.x;
    // Wih pack [3 g][8 wv][20 kc][64 lane][8]: lane=(q<<5)|l31, col=wv*32+l31, k0=kc*16+q*8
    for (int i = tid; i < 3*8*20*64; i += nthr){
        const int lane = i & 63;
        const int t2   = i >> 6;
        const int kc   = t2 % 20;
        const int wvg  = t2 / 20;          // g*8 + wv
        const int g    = wvg >> 3, wv = wvg & 7;
        const int col  = wv*32 + (lane & 31);
        const int k0   = kc*16 + (lane >> 5)*8;
        const float* sF = Wih_f + (size_t)(g*NH + col)*NE;
        const float* sB = Wih_b + (size_t)(g*NH + col)*NE;
        u16* dF = WihF_p + (size_t)i*8;
        u16* dB = WihB_p + (size_t)i*8;
        #pragma unroll
        for (int j = 0; j < 8; j++){
            const int k = k0 + j;
            dF[j] = (k < NE) ? f2bf(sF[k]) : (u16)0;
            dB[j] = (k < NE) ? f2bf(sB[k]) : (u16)0;
        }
    }
    // Whh pack [3 g][16 wv][8 kc][64 lane][8]: col=wv*16+l15, k0=kc*32+q*8 (MFMA16 frag)
    for (int i = tid; i < 3*16*8*64; i += nthr){
        const int lane = i & 63;
        const int kc   = (i >> 6) & 7;
        const int wvg  = i >> 9;           // g*16 + wv
        const int g    = wvg >> 4, wv = wvg & 15;
        const int l15  = lane & 15, q = lane >> 4;
        const int col  = wv*16 + l15;
        const int k0   = kc*32 + q*8;
        const float* srcF = Whh_f + (size_t)(g*NH + col)*NH + k0;
        const float* srcB = Whh_b + (size_t)(g*NH + col)*NH + k0;
        u16* dF = WhhF_p + (size_t)i*8;
        u16* dB = WhhB_p + (size_t)i*8;
        #pragma unroll
        for (int j = 0; j < 8; j++){ dF[j] = f2bf(srcF[j]); dB[j] = f2bf(srcB[j]); }
    }
    // mlpW pack [2 nt][8 wv][32 kc][64 lane][8]: row=wv*64+nt*32+l31, k0=kc*16+q*8
    for (int i = tid; i < 2*8*32*64; i += nthr){
        const int lane = i & 63;
        const int t2   = i >> 6;
        const int kc   = t2 & 31;
        const int ntwv = t2 >> 5;          // nt*8 + wv
        const int nt   = ntwv >> 3, wv = ntwv & 7;
        const int row  = wv*64 + nt*32 + (lane & 31);
        const int k0   = kc*16 + (lane >> 5)*8;
        const float* s = mlpW + (size_t)row*512 + k0;
        u16* d = mlpW_p + (size_t)i*8;
        #pragma unroll
        for (int j = 0; j < 8; j++) d[j] = f2bf(s[j]);
    }
    for (int i = tid; i < 512; i += nthr){ bnSum[i] = 0.0f; bnSumSq[i] = 0.0f; }
    for (int i = tid; i < NB*512; i += nthr) pooled_u[i] = 0u;
}

// ---------------- eproj: split xprojRZ (u32: r|z<<16) + xprojN (u16) ----------------
__global__ __launch_bounds__(512, 4)
void eproj_kernel(const int* __restrict__ x, const float* __restrict__ emb,
                  const u16* __restrict__ Wih_p, const float* __restrict__ b_ih,
                  const float* __restrict__ b_hh,
                  u32* __restrict__ xprojRZ, u16* __restrict__ xprojN)
{
    __shared__ u16 a_lds[MRE*328];
    const int tid = threadIdx.x;
    const int mb  = blockIdx.x;       // 0..513
    {
        const int row = tid >> 4, jj = tid & 15;
        const int flat = mb*MRE + row;
        const int t_id = (flat < NCELL) ? x[flat] : 0;
        const float4* src = (const float4*)(emb + (size_t)t_id*NE);
        u16* dst = a_lds + row*328;
        for (int idx = jj; idx < 75; idx += 16){
            float4 v = src[idx];
            ushort4 o; o.x=f2bf(v.x); o.y=f2bf(v.y); o.z=f2bf(v.z); o.w=f2bf(v.w);
            *(ushort4*)(dst + idx*4) = o;
        }
        if (jj == 15){
            const ushort4 z = {0,0,0,0};
            #pragma unroll
            for (int c = 300; c < 320; c += 4) *(ushort4*)(dst + c) = z;
        }
    }
    __syncthreads();

    const int lane = tid & 63, wv = tid >> 6, l31 = lane & 31, q = lane >> 5;
    const int col = wv*32 + l31;
    f32x16 acc[3];
    #pragma unroll
    for (int g = 0; g < 3; g++)
        #pragma unroll
        for (int i = 0; i < 16; i++) acc[g][i] = 0.0f;

    const u16* a0p = a_lds + l31*328 + q*8;
    // fragment-packed Wih: coalesced base+lane*16
    const char* wf0 = (const char*)Wih_p + (size_t)((0*8 + wv)*20)*1024 + (size_t)lane*16;
    const char* wf1 = (const char*)Wih_p + (size_t)((1*8 + wv)*20)*1024 + (size_t)lane*16;
    const char* wf2 = (const char*)Wih_p + (size_t)((2*8 + wv)*20)*1024 + (size_t)lane*16;

    #pragma unroll 4
    for (int kc = 0; kc < 20; kc++){
        bf16x8 a0 = *(const bf16x8*)(a0p + kc*16);
        bf16x8 b0 = *(const bf16x8*)(wf0 + kc*1024);
        bf16x8 b1 = *(const bf16x8*)(wf1 + kc*1024);
        bf16x8 b2 = *(const bf16x8*)(wf2 + kc*1024);
        acc[0] = MFMA32(a0,b0,acc[0],0,0,0);
        acc[1] = MFMA32(a0,b1,acc[1],0,0,0);
        acc[2] = MFMA32(a0,b2,acc[2],0,0,0);
    }
    const float br  = b_ih[col]      + b_hh[col];
    const float bz  = b_ih[NH+col]   + b_hh[NH+col];
    const float bn_ = b_ih[2*NH+col];
    #pragma unroll
    for (int r = 0; r < 16; r++){
        const int rit = (r&3) + 8*(r>>2) + 4*q;
        const int row = mb*MRE + rit;
        const u32 rzv = (u32)f2bf(acc[0][r] + br) | ((u32)f2bf(acc[1][r] + bz) << 16);
        xprojRZ[(size_t)row*256 + col] = rzv;
        xprojN [(size_t)row*256 + col] = f2bf(acc[2][r] + bn_);
    }
}

// ---------------- recurrence v13: double-buffered h, 1 barrier/step, N from L2 ----------------
// v12 PMC: FETCH minimal (26.7MB), spill-free, but 2 barriers/step (single h buffer forced
// by LDS: rz 81K + n 41K + h 34K). ~37% of each step neither-pipe-busy = barrier drain.
// Fix: evict only xprojN from LDS. Per-XCD N working set = 2048 rows x 512B = 1.05MB ->
// L2-resident next to Whh (384KB) under the XCD-sliced mb mapping (mechanism verified:
// failed at 4.2MB/XCD in round 2, works at <=3MB since). LDS = rz 81.1K + 2x h 67.6K
// = 149K -> h double-buffer restores the round-0 single-barrier schedule. N gate loads:
// 16 batched u16 from L2 inside the gate phase (NO registers live across the MFMA phase
// -- the rounds-4/5 spill trap), ~2x250cy exposed, ~3 VALU/load clamp.
__global__ __launch_bounds__(1024, 4)
void recur_kernel(const int* __restrict__ x,
                  const u32* __restrict__ xprojRZ, const u16* __restrict__ xprojN,
                  const u16* __restrict__ Whh_p, const float* __restrict__ b_hh,
                  u16* __restrict__ hidden, float* __restrict__ bnSum, float* __restrict__ bnSumSq,
                  int dir)
{
    __shared__ u32 rz_lds[WROWS*RZS];   // 81120 B
    __shared__ u16 hb[2][MRR*HS];       // 2 x 33792 B
    __shared__ float maskv[MRR];        // total 149216 B < 160K
    const int tid = threadIdx.x;
    const int bid = blockIdx.x;       // 0..255
    const int mb  = ((bid & 7) << 5) | (bid >> 3);   // XCD -> contiguous 2048-row xproj slice
    if (tid < MRR) maskv[tid] = (x[mb*MRR + tid] > 0) ? 1.0f : 0.0f;

    const int bidx = (mb*MRR) >> 9;
    const int s0   = (mb*MRR) & (NS-1);
    const int joff = s0 + (dir ? 0 : -(NW-1));       // window row w -> seq index j = joff + w

    // ---- stage the 78-row RZ window (clamped rows -> pad row NCELL = token-0 projection) ----
    for (int i = tid; i < WROWS*64; i += 1024){
        const int w = i >> 6, c4 = i & 63;
        const int j = joff + w;
        const size_t row = ((unsigned)j < (unsigned)NS) ? (size_t)(bidx*NS + j) : (size_t)NCELL;
        const uint4 v = *(const uint4*)(xprojRZ + row*256 + c4*4);
        *(uint4*)(rz_lds + w*RZS + c4*4) = v;
    }
    __syncthreads();

    const int lane = tid & 63, wv = tid >> 6;        // wv 0..15
    const int l15 = lane & 15, q = lane >> 4;        // q 0..3
    const int col  = wv*16 + l15;                    // hidden column 0..255

    const float bhn = b_hh[2*NH + col];

    // fragment-packed W_hh: wave's stream base, gate at +g*131072, kc at +kc*1024
    const char* wf = (const char*)Whh_p + ((size_t)wv << 13) + ((size_t)lane << 4);

    // A-frag LDS offset: row (mt*16 + l15), k = kc*32 + q*8
    const int haOff = l15*HS + q*8;
    // rz gate-read dynamic base (per-thread); (mt*16+r)*RZS fits DS imm offset
    const u32* rzp0 = rz_lds + q*4*RZS + col;
    // N global byte bases (L2-resident per-XCD slice)
    const char* xnb = (const char*)xprojN;
    const u32 colN  = (u32)(col * 2);
    const u32 rowBaseN = (u32)(bidx * NS) * 512u;
    const u32 padN  = (u32)NCELL * 512u + colN;      // pad row = token-0 projection

    float hreg[16];
    #pragma unroll
    for (int i = 0; i < 16; i++) hreg[i] = 0.0f;

    #pragma unroll 1
    for (int t = 0; t < NW; t++){
        f32x4 acc[4][3];
        #pragma unroll
        for (int mt = 0; mt < 4; mt++)
            #pragma unroll
            for (int g = 0; g < 3; g++)
                #pragma unroll
                for (int i = 0; i < 4; i++) acc[mt][g][i] = (g == 2) ? bhn : 0.0f;

        if (t > 0){
            const u16* hcur = hb[t & 1] + haOff;
            // B pipelined one kc ahead of consumption (coalesced fragment loads, L2-hot)
            bf16x8 b0 = *(const bf16x8*)(wf + 0*131072);
            bf16x8 b1 = *(const bf16x8*)(wf + 1*131072);
            bf16x8 b2 = *(const bf16x8*)(wf + 2*131072);
            #pragma unroll
            for (int kc = 0; kc < 8; kc++){
                bf16x8 n0, n1, n2;
                if (kc < 7){
                    const int ko = (kc+1)*1024;
                    n0 = *(const bf16x8*)(wf + 0*131072 + ko);
                    n1 = *(const bf16x8*)(wf + 1*131072 + ko);
                    n2 = *(const bf16x8*)(wf + 2*131072 + ko);
                }
                bf16x8 a0 = *(const bf16x8*)(hcur + kc*32 +   0);
                bf16x8 a1 = *(const bf16x8*)(hcur + kc*32 + 16*HS);
                bf16x8 a2 = *(const bf16x8*)(hcur + kc*32 + 32*HS);
                bf16x8 a3 = *(const bf16x8*)(hcur + kc*32 + 48*HS);
                acc[0][0] = MFMA16(a0,b0,acc[0][0],0,0,0);
                acc[1][0] = MFMA16(a1,b0,acc[1][0],0,0,0);
                acc[2][0] = MFMA16(a2,b0,acc[2][0],0,0,0);
                acc[3][0] = MFMA16(a3,b0,acc[3][0],0,0,0);
                acc[0][1] = MFMA16(a0,b1,acc[0][1],0,0,0);
                acc[1][1] = MFMA16(a1,b1,acc[1][1],0,0,0);
                acc[2][1] = MFMA16(a2,b1,acc[2][1],0,0,0);
                acc[3][1] = MFMA16(a3,b1,acc[3][1],0,0,0);
                acc[0][2] = MFMA16(a0,b2,acc[0][2],0,0,0);
                acc[1][2] = MFMA16(a1,b2,acc[1][2],0,0,0);
                acc[2][2] = MFMA16(a2,b2,acc[2][2],0,0,0);
                acc[3][2] = MFMA16(a3,b2,acc[3][2],0,0,0);
                if (kc < 7){ b0 = n0; b1 = n1; b2 = n2; }
            }
        }
        // gate phase — N: 16 batched u16 loads from L2 (issued first, one latency exposure);
        // rz: LDS imm-offset reads in 2 batches of 8; hw-exp math
        const int wbase = (dir == 0) ? t : ((NW-1) - t);
        const int jbase = joff + wbase;
        u16 nn[16];
        #pragma unroll
        for (int i = 0; i < 16; i++){
            const int mt = i >> 2, r = i & 3;
            const int j = jbase + mt*16 + q*4 + r;
            const u32 off = ((unsigned)j < (unsigned)NS) ? (rowBaseN + (u32)j*512u + colN) : padN;
            nn[i] = *(const u16*)(xnb + off);
        }
        const u32* rzp = rzp0 + wbase*RZS;
        #pragma unroll
        for (int half = 0; half < 2; half++){
            u32 rz[8];
            #pragma unroll
            for (int i = 0; i < 8; i++){
                const int ii = half*8 + i;
                const int mt = ii >> 2, r = ii & 3;
                rz[i] = rzp[(mt*16 + r)*RZS];
            }
            #pragma unroll
            for (int i = 0; i < 8; i++){
                const int ii = half*8 + i;
                const int mt = ii >> 2, r = ii & 3;
                const float xr = bf2f((u16)(rz[i] & 0xFFFFu));
                const float xz = bf2f((u16)(rz[i] >> 16));
                const float xn = bf2f(nn[ii]);
                const float rg = sigm_hw(xr + acc[mt][0][r]);
                const float zg = sigm_hw(xz + acc[mt][1][r]);
                const float ng = tanh_hw(fmaf(rg, acc[mt][2][r], xn));
                hreg[ii] = fmaf(zg, hreg[ii] - ng, ng);
            }
        }
        if (t + 1 < NW){
            u16* hw = hb[(t + 1) & 1];
            #pragma unroll
            for (int mt = 0; mt < 4; mt++)
                #pragma unroll
                for (int r = 0; r < 4; r++){
                    const int rit = mt*16 + q*4 + r;
                    hw[rit*HS + col] = f2bf_rh(hreg[mt*4 + r]);
                }
            __syncthreads();                 // single barrier/step: double-buffered h
        }
    }
    // epilogue: mask, store hidden (bf16), BN partial sums
    float sum = 0.0f, sumsq = 0.0f;
    #pragma unroll
    for (int mt = 0; mt < 4; mt++)
        #pragma unroll
        for (int r = 0; r < 4; r++){
            const int rit = mt*16 + q*4 + r;
            const float hm = hreg[mt*4 + r] * maskv[rit];
            hidden[(size_t)(mb*MRR + rit)*512 + dir*NH + col] = f2bf(hm);
            sum += hm; sumsq += hm*hm;
        }
    // reduce across q (lanes l15, l15+16, l15+32, l15+48 share a col)
    sum   += __shfl_xor(sum, 16);   sumsq += __shfl_xor(sumsq, 16);
    sum   += __shfl_xor(sum, 32);   sumsq += __shfl_xor(sumsq, 32);
    if (q == 0){
        atomicAdd(&bnSum[dir*NH + col], sum);
        atomicAdd(&bnSumSq[dir*NH + col], sumsq);
    }
}

// ---------------- BN finalize ----------------
__global__ void bnfin_kernel(const float* __restrict__ bnSum, const float* __restrict__ bnSumSq,
                             const float* __restrict__ gamma, const float* __restrict__ beta,
                             float* __restrict__ bnScale, float* __restrict__ bnShift)
{
    const int c = blockIdx.x*blockDim.x + threadIdx.x;
    if (c < 512){
        const float mu  = bnSum[c]   * (1.0f/16384.0f);
        const float var = bnSumSq[c] * (1.0f/16384.0f) - mu*mu;
        const float inv = rsqrtf(var + 1e-5f);
        const float sc  = gamma[c]*inv;
        bnScale[c] = sc;
        bnShift[c] = beta[c] - mu*sc;
    }
}

// ---------------- MLP + mask + max-pool ----------------
__global__ __launch_bounds__(512, 4)
void mlp_kernel(const int* __restrict__ x, const u16* __restrict__ hidden,
                const u16* __restrict__ mlpW_p, const float* __restrict__ bnScale,
                const float* __restrict__ bnShift, const float* __restrict__ mlp_b,
                unsigned* __restrict__ pooled_u)
{
    __shared__ u16 a_lds[MRE*520];
    __shared__ float maskv[MRE];
    const int tid = threadIdx.x;
    const int mb  = blockIdx.x;     // 0..511
    if (tid < MRE) maskv[tid] = (x[mb*MRE + tid] > 0) ? 1.0f : 0.0f;
    __syncthreads();
    {
        const int row = tid >> 4, jj = tid & 15;
        const float m = maskv[row];
        const u16* src = hidden + (size_t)(mb*MRE + row)*512;
        u16* dst = a_lds + row*520;
        for (int c4 = jj; c4 < 128; c4 += 16){
            ushort4 v = ((const ushort4*)src)[c4];
            const int c = c4*4;
            float4 sc = *(const float4*)(bnScale + c);
            float4 sh = *(const float4*)(bnShift + c);
            ushort4 o;
            o.x = f2bf((bf2f(v.x)*sc.x + sh.x)*m);
            o.y = f2bf((bf2f(v.y)*sc.y + sh.y)*m);
            o.z = f2bf((bf2f(v.z)*sc.z + sh.z)*m);
            o.w = f2bf((bf2f(v.w)*sc.w + sh.w)*m);
            *(ushort4*)(dst + c) = o;
        }
    }
    __syncthreads();

    const int lane = tid & 63, wv = tid >> 6, l31 = lane & 31, q = lane >> 5;
    f32x16 acc[2];
    #pragma unroll
    for (int g = 0; g < 2; g++)
        #pragma unroll
        for (int i = 0; i < 16; i++) acc[g][i] = 0.0f;

    const u16* a0p = a_lds + l31*520 + q*8;
    // fragment-packed mlpW: coalesced base+lane*16
    const char* wm0 = (const char*)mlpW_p + (size_t)((0*8 + wv)*32)*1024 + (size_t)lane*16;
    const char* wm1 = (const char*)mlpW_p + (size_t)((1*8 + wv)*32)*1024 + (size_t)lane*16;

    #pragma unroll 4
    for (int kc = 0; kc < 32; kc++){
        bf16x8 a0 = *(const bf16x8*)(a0p + kc*16);
        bf16x8 b0 = *(const bf16x8*)(wm0 + kc*1024);
        bf16x8 b1 = *(const bf16x8*)(wm1 + kc*1024);
        acc[0] = MFMA32(a0,b0,acc[0],0,0,0);
        acc[1] = MFMA32(a0,b1,acc[1],0,0,0);
    }

    const int bidx = mb >> 4;
    #pragma unroll
    for (int nt = 0; nt < 2; nt++){
        const int colg = wv*64 + nt*32 + l31;
        const float bias = mlp_b[colg];
        float mx = -3.4e38f;
        #pragma unroll
        for (int r = 0; r < 16; r++){
            const int rit = (r&3) + 8*(r>>2) + 4*q;
            const float m = maskv[rit];
            const float v = (acc[nt][r] + bias)*m + (m - 1.0f)*65500.0f;
            mx = fmaxf(mx, v);
        }
        mx = fmaxf(mx, __shfl_xor(mx, 32));
        if (q == 0) atomicMax(&pooled_u[bidx*512 + colg], fkey(mx));
    }
}

// ---------------- final linear [32x512] @ [512x2] ----------------
__global__ void final_kernel(const unsigned* __restrict__ pooled_u,
                             const float* __restrict__ linW, const float* __restrict__ linb,
                             float* __restrict__ out)
{
    const int b = blockIdx.x;       // 32
    const int lane = threadIdx.x;   // 64
    float s0 = 0.0f, s1 = 0.0f;
    for (int c = lane; c < 512; c += 64){
        const unsigned u = pooled_u[b*512 + c];
        const unsigned bits = (u & 0x80000000u) ? (u ^ 0x80000000u) : ~u;
        const float f = __uint_as_float(bits);
        s0 += f * linW[c];
        s1 += f * linW[512 + c];
    }
    #pragma unroll
    for (int off = 32; off > 0; off >>= 1){
        s0 += __shfl_xor(s0, off);
        s1 += __shfl_xor(s1, off);
    }
    if (lane == 0){ out[2*b] = s0 + linb[0]; out[2*b + 1] = s1 + linb[1]; }
}

extern "C" void kernel_launch(void* const* d_in, const int* in_sizes, int n_in,
                              void* d_out, int out_size, void* d_ws, size_t ws_size,
                              hipStream_t stream)
{
    const int*   x     = (const int*)  d_in[0];
    const float* emb   = (const float*)d_in[5];
    const float* Wih_f = (const float*)d_in[6];
    const float* Whh_f = (const float*)d_in[7];
    const float* bih_f = (const float*)d_in[8];
    const float* bhh_f = (const float*)d_in[9];
    const float* Wih_b = (const float*)d_in[10];
    const float* Whh_b = (const float*)d_in[11];
    const float* bih_b = (const float*)d_in[12];
    const float* bhh_b = (const float*)d_in[13];
    const float* gamma = (const float*)d_in[14];
    const float* beta  = (const float*)d_in[15];
    const float* mlpW  = (const float*)d_in[16];
    const float* mlpb  = (const float*)d_in[17];
    const float* linW  = (const float*)d_in[18];
    const float* linb  = (const float*)d_in[19];
    float* out = (float*)d_out;
    char* ws = (char*)d_ws;

    u16*   WihF_p  = (u16*)  (ws + 0);           // packed, 491520 B
    u16*   WihB_p  = (u16*)  (ws + 491520);
    u16*   WhhF_p  = (u16*)  (ws + 983040);      // fragment-packed, 393216 B
    u16*   WhhB_p  = (u16*)  (ws + 1376256);
    u16*   mlpW_p  = (u16*)  (ws + 1769472);     // packed, 524288 B
    float* bnSum   = (float*)(ws + 2293760);
    float* bnSumSq = (float*)(ws + 2295808);
    float* bnScale = (float*)(ws + 2297856);
    float* bnShift = (float*)(ws + 2299904);
    unsigned* pooled_u = (unsigned*)(ws + 2301952);
    u16*   hidden  = (u16*)  (ws + 2367488);     // 16384x512 bf16
    u32*   xprojRZ = (u32*)  (ws + 19144704);    // 16448x256 u32 (r|z<<16), 16842752 B
    u16*   xprojN  = (u16*)  (ws + 35987456);    // 16448x256 u16, 8421376 B

    prep_kernel<<<512, 256, 0, stream>>>(Wih_f, Wih_b, Whh_f, Whh_b, mlpW,
                                         WihF_p, WihB_p, WhhF_p, WhhB_p, mlpW_p,
                                         bnSum, bnSumSq, pooled_u);
    // forward direction
    eproj_kernel<<<514, 512, 0, stream>>>(x, emb, WihF_p, bih_f, bhh_f, xprojRZ, xprojN);
    recur_kernel<<<256, 1024, 0, stream>>>(x, xprojRZ, xprojN, WhhF_p, bhh_f, hidden, bnSum, bnSumSq, 0);
    // backward direction (reuses xproj buffers)
    eproj_kernel<<<514, 512, 0, stream>>>(x, emb, WihB_p, bih_b, bhh_b, xprojRZ, xprojN);
    recur_kernel<<<256, 1024, 0, stream>>>(x, xprojRZ, xprojN, WhhB_p, bhh_b, hidden, bnSum, bnSumSq, 1);

    bnfin_kernel<<<2, 256, 0, stream>>>(bnSum, bnSumSq, gamma, beta, bnScale, bnShift);
    mlp_kernel<<<512, 512, 0, stream>>>(x, hidden, mlpW_p, bnScale, bnShift, mlpb, pooled_u);
    final_kernel<<<32, 64, 0, stream>>>(pooled_u, linW, linb, out);
}

// Round 8
// 465.749 us; speedup vs baseline: 1.4151x; 1.4151x over previous
//
#include <hip/hip_runtime.h>
#include <hip/hip_bf16.h>
#include <stdint.h>

// DRNN_75204877353433: windowed bidirectional GRU (W=15) + BN + MLP + masked maxpool + linear
// B=32 S=512 W=15 E=300 H=256 V=50000 C=2, G=3H=768

typedef unsigned short u16;
typedef unsigned int u32;
typedef float f32x16 __attribute__((ext_vector_type(16)));
typedef float f32x4  __attribute__((ext_vector_type(4)));
typedef short bf16x8 __attribute__((ext_vector_type(8)));

#define MFMA32 __builtin_amdgcn_mfma_f32_32x32x16_bf16
#define MFMA16 __builtin_amdgcn_mfma_f32_16x16x32_bf16

#define NB 32
#define NS 512
#define NW 15
#define NE 300
#define NH 256
#define NG 768
#define NCELL (NB*NS)   // 16384
#define EPAD 320        // E padded to multiple of 16
#define MRE 32          // rows per block in eproj/mlp
#define MRR 64          // rows per block in recur
#define HS 264          // h_lds row stride (u16)
#define WROWS 78        // xproj window rows per block (64 + 14)
#define RZS 260         // rz_lds row stride (u32)
#define NSS 264         // n_lds row stride (u16)

__device__ __forceinline__ float bf2f(u16 u){
    union { unsigned int i; float f; } v; v.i = ((unsigned int)u) << 16; return v.f;
}
__device__ __forceinline__ u16 f2bf(float f){
    union { float f; unsigned int i; } v; v.f = f;
    unsigned int x = v.i;
    x += 0x7fffu + ((x >> 16) & 1u);   // RNE
    return (u16)(x >> 16);
}
__device__ __forceinline__ u16 f2bf_rh(float f){   // round-half-up, 2 VALU ops
    return (u16)((__float_as_uint(f) + 0x8000u) >> 16);
}
__device__ __forceinline__ unsigned fkey(float f){   // order-preserving float->uint map
    unsigned b = __float_as_uint(f);
    return b ^ ((b & 0x80000000u) ? 0xFFFFFFFFu : 0x80000000u);
}

// ---- hw transcendental gate math (validated round 1): short chains, saturating edges ----
__device__ __forceinline__ float sigm_hw(float x){   // 1/(1+2^(-x*log2e))
    return __builtin_amdgcn_rcpf(1.0f + __builtin_amdgcn_exp2f(x * -1.44269504f));
}
__device__ __forceinline__ float tanh_hw(float x){   // 1 - 2/(1+2^(2x*log2e))
    return fmaf(-2.0f, __builtin_amdgcn_rcpf(1.0f + __builtin_amdgcn_exp2f(x * 2.88539008f)), 1.0f);
}

// ---------------- prep ----------------
// ALL MFMA B-operands fragment-packed: per (plane, wave, kc) a contiguous 1KB block,
// element addr = base + lane*16B -> coalesced dwordx4 loads everywhere.
__global__ void prep_kernel(const float* __restrict__ Wih_f, const float* __restrict__ Wih_b,
                            const float* __restrict__ Whh_f, const float* __restrict__ Whh_b,
                            const float* __restrict__ mlpW,
                            u16* __restrict__ WihF_p, u16* __restrict__ WihB_p,
                            u16* __restrict__ WhhF_p, u16* __restrict__ WhhB_p,
                            u16* __restrict__ mlpW_p,
                            float* __restrict__ bnSum, float* __restrict__ bnSumSq,
                            unsigned* __restrict__ pooled_u)
{
    const int tid  = blockIdx.x*blockDim.x + threadIdx.x;
    const int nthr = gridDim.x*blockDim.x;
    // Wih pack [3 g][8 wv][20 kc][64 lane][8]: lane=(q<<5)|l31, col=wv*32+l31, k0=kc*16+q*8
    for (int i = tid; i < 3*8*20*64; i += nthr){
        const int lane = i & 63;
        const int t2   = i >> 6;
        const int kc   = t2 % 20;
        const int wvg  = t2 / 20;          // g*8 + wv
        const int g    = wvg >> 3, wv = wvg & 7;
        const int col  = wv*32 + (lane & 31);
        const int k0   = kc*16 + (lane >> 5)*8;
        const float* sF = Wih_f + (size_t)(g*NH + col)*NE;
        const float* sB = Wih_b + (size_t)(g*NH + col)*NE;
        u16* dF = WihF_p + (size_t)i*8;
        u16* dB = WihB_p + (size_t)i*8;
        #pragma unroll
        for (int j = 0; j < 8; j++){
            const int k = k0 + j;
            dF[j] = (k < NE) ? f2bf(sF[k]) : (u16)0;
            dB[j] = (k < NE) ? f2bf(sB[k]) : (u16)0;
        }
    }
    // Whh pack [3 g][16 wv][8 kc][64 lane][8]: col=wv*16+l15, k0=kc*32+q*8 (MFMA16 frag)
    for (int i = tid; i < 3*16*8*64; i += nthr){
        const int lane = i & 63;
        const int kc   = (i >> 6) & 7;
        const int wvg  = i >> 9;           // g*16 + wv
        const int g    = wvg >> 4, wv = wvg & 15;
        const int l15  = lane & 15, q = lane >> 4;
        const int col  = wv*16 + l15;
        const int k0   = kc*32 + q*8;
        const float* srcF = Whh_f + (size_t)(g*NH + col)*NH + k0;
        const float* srcB = Whh_b + (size_t)(g*NH + col)*NH + k0;
        u16* dF = WhhF_p + (size_t)i*8;
        u16* dB = WhhB_p + (size_t)i*8;
        #pragma unroll
        for (int j = 0; j < 8; j++){ dF[j] = f2bf(srcF[j]); dB[j] = f2bf(srcB[j]); }
    }
    // mlpW pack [2 nt][8 wv][32 kc][64 lane][8]: row=wv*64+nt*32+l31, k0=kc*16+q*8
    for (int i = tid; i < 2*8*32*64; i += nthr){
        const int lane = i & 63;
        const int t2   = i >> 6;
        const int kc   = t2 & 31;
        const int ntwv = t2 >> 5;          // nt*8 + wv
        const int nt   = ntwv >> 3, wv = ntwv & 7;
        const int row  = wv*64 + nt*32 + (lane & 31);
        const int k0   = kc*16 + (lane >> 5)*8;
        const float* s = mlpW + (size_t)row*512 + k0;
        u16* d = mlpW_p + (size_t)i*8;
        #pragma unroll
        for (int j = 0; j < 8; j++) d[j] = f2bf(s[j]);
    }
    for (int i = tid; i < 512; i += nthr){ bnSum[i] = 0.0f; bnSumSq[i] = 0.0f; }
    for (int i = tid; i < NB*512; i += nthr) pooled_u[i] = 0u;
}

// ---------------- eproj FUSED (both directions): split xprojRZ + xprojN ----------------
// Grid 1028 = 2x514: the old 514-block grid on 256 CUs ran 2 full rounds + a 2-block
// tail round (254 CUs idle); fusing both directions into one dispatch saves one tail
// round + one launch boundary.
__global__ __launch_bounds__(512, 4)
void eproj_kernel(const int* __restrict__ x, const float* __restrict__ emb,
                  const u16* __restrict__ WihF_p, const u16* __restrict__ WihB_p,
                  const float* __restrict__ bih_f, const float* __restrict__ bhh_f,
                  const float* __restrict__ bih_b, const float* __restrict__ bhh_b,
                  u32* __restrict__ rzF, u16* __restrict__ nF,
                  u32* __restrict__ rzB, u16* __restrict__ nB)
{
    __shared__ u16 a_lds[MRE*328];
    const int tid = threadIdx.x;
    const int dir = (blockIdx.x >= 514);
    const int mb  = dir ? (blockIdx.x - 514) : blockIdx.x;   // 0..513
    const u16* Wih_p = dir ? WihB_p : WihF_p;
    const float* b_ih = dir ? bih_b : bih_f;
    const float* b_hh = dir ? bhh_b : bhh_f;
    u32* xprojRZ = dir ? rzB : rzF;
    u16* xprojN  = dir ? nB  : nF;
    {
        const int row = tid >> 4, jj = tid & 15;
        const int flat = mb*MRE + row;
        const int t_id = (flat < NCELL) ? x[flat] : 0;
        const float4* src = (const float4*)(emb + (size_t)t_id*NE);
        u16* dst = a_lds + row*328;
        for (int idx = jj; idx < 75; idx += 16){
            float4 v = src[idx];
            ushort4 o; o.x=f2bf(v.x); o.y=f2bf(v.y); o.z=f2bf(v.z); o.w=f2bf(v.w);
            *(ushort4*)(dst + idx*4) = o;
        }
        if (jj == 15){
            const ushort4 z = {0,0,0,0};
            #pragma unroll
            for (int c = 300; c < 320; c += 4) *(ushort4*)(dst + c) = z;
        }
    }
    __syncthreads();

    const int lane = tid & 63, wv = tid >> 6, l31 = lane & 31, q = lane >> 5;
    const int col = wv*32 + l31;
    f32x16 acc[3];
    #pragma unroll
    for (int g = 0; g < 3; g++)
        #pragma unroll
        for (int i = 0; i < 16; i++) acc[g][i] = 0.0f;

    const u16* a0p = a_lds + l31*328 + q*8;
    // fragment-packed Wih: coalesced base+lane*16
    const char* wf0 = (const char*)Wih_p + (size_t)((0*8 + wv)*20)*1024 + (size_t)lane*16;
    const char* wf1 = (const char*)Wih_p + (size_t)((1*8 + wv)*20)*1024 + (size_t)lane*16;
    const char* wf2 = (const char*)Wih_p + (size_t)((2*8 + wv)*20)*1024 + (size_t)lane*16;

    #pragma unroll 4
    for (int kc = 0; kc < 20; kc++){
        bf16x8 a0 = *(const bf16x8*)(a0p + kc*16);
        bf16x8 b0 = *(const bf16x8*)(wf0 + kc*1024);
        bf16x8 b1 = *(const bf16x8*)(wf1 + kc*1024);
        bf16x8 b2 = *(const bf16x8*)(wf2 + kc*1024);
        acc[0] = MFMA32(a0,b0,acc[0],0,0,0);
        acc[1] = MFMA32(a0,b1,acc[1],0,0,0);
        acc[2] = MFMA32(a0,b2,acc[2],0,0,0);
    }
    const float br  = b_ih[col]      + b_hh[col];
    const float bz  = b_ih[NH+col]   + b_hh[NH+col];
    const float bn_ = b_ih[2*NH+col];
    #pragma unroll
    for (int r = 0; r < 16; r++){
        const int rit = (r&3) + 8*(r>>2) + 4*q;
        const int row = mb*MRE + rit;
        const u32 rzv = (u32)f2bf(acc[0][r] + br) | ((u32)f2bf(acc[1][r] + bz) << 16);
        xprojRZ[(size_t)row*256 + col] = rzv;
        xprojN [(size_t)row*256 + col] = f2bf(acc[2][r] + bn_);
    }
}

// ---------------- recurrence v14: v12 body (verified 164us), FUSED both directions ----------------
// Round-7 falsified L2-residency for ANY per-step window stream (N-from-L2: FETCH
// 26.7->350MB, +74us) -> everything per-step stays in LDS, 2 barriers/step is the
// geometric floor (window 117K + 2xh 135K > 160K in all ring/dbuf variants).
// Fusion: grid 512, dir = bid>>8 -> per-CU back-to-back blocks remove the inter-dispatch
// drain and smooth finish skew. Inner loop byte-identical to verified v12.
__global__ __launch_bounds__(1024, 4)
void recur_kernel(const int* __restrict__ x,
                  const u32* __restrict__ rzF, const u16* __restrict__ nF,
                  const u32* __restrict__ rzB, const u16* __restrict__ nB,
                  const u16* __restrict__ WhhF_p, const u16* __restrict__ WhhB_p,
                  const float* __restrict__ bhh_f, const float* __restrict__ bhh_b,
                  u16* __restrict__ hidden, float* __restrict__ bnSum, float* __restrict__ bnSumSq)
{
    __shared__ u32 rz_lds[WROWS*RZS];   // 81120 B
    __shared__ u16 n_lds [WROWS*NSS];   // 41184 B
    __shared__ u16 h_lds [MRR*HS];      // 33792 B
    __shared__ float maskv[MRR];
    const int tid = threadIdx.x;
    const int bid = blockIdx.x & 255;    // 0..255 within direction
    const int dir = blockIdx.x >> 8;     // 0 fwd, 1 bwd
    const u32* xprojRZ = dir ? rzB : rzF;
    const u16* xprojN  = dir ? nB  : nF;
    const u16* Whh_p   = dir ? WhhB_p : WhhF_p;
    const float* b_hh  = dir ? bhh_b : bhh_f;
    const int mb  = ((bid & 7) << 5) | (bid >> 3);   // XCD -> contiguous 2048-row xproj slice
    if (tid < MRR) maskv[tid] = (x[mb*MRR + tid] > 0) ? 1.0f : 0.0f;

    const int bidx = (mb*MRR) >> 9;
    const int s0   = (mb*MRR) & (NS-1);
    const int joff = s0 + (dir ? 0 : -(NW-1));       // window row w -> seq index j = joff + w

    // ---- stage the 78-row window (clamped rows -> pad row NCELL = token-0 projection) ----
    for (int i = tid; i < WROWS*64; i += 1024){
        const int w = i >> 6, c4 = i & 63;
        const int j = joff + w;
        const size_t row = ((unsigned)j < (unsigned)NS) ? (size_t)(bidx*NS + j) : (size_t)NCELL;
        const uint4 v = *(const uint4*)(xprojRZ + row*256 + c4*4);
        *(uint4*)(rz_lds + w*RZS + c4*4) = v;
    }
    for (int i = tid; i < WROWS*32; i += 1024){
        const int w = i >> 5, c8 = i & 31;
        const int j = joff + w;
        const size_t row = ((unsigned)j < (unsigned)NS) ? (size_t)(bidx*NS + j) : (size_t)NCELL;
        const uint4 v = *(const uint4*)(xprojN + row*256 + c8*8);
        *(uint4*)(n_lds + w*NSS + c8*8) = v;
    }
    __syncthreads();

    const int lane = tid & 63, wv = tid >> 6;        // wv 0..15
    const int l15 = lane & 15, q = lane >> 4;        // q 0..3
    const int col  = wv*16 + l15;                    // hidden column 0..255

    const float bhn = b_hh[2*NH + col];

    // fragment-packed W_hh: wave's stream base, gate at +g*131072, kc at +kc*1024
    const char* wf = (const char*)Whh_p + ((size_t)wv << 13) + ((size_t)lane << 4);

    // A-frag LDS offset: row (mt*16 + l15), k = kc*32 + q*8
    const int haOff = l15*HS + q*8;
    // gate-read dynamic bases (per-thread); (mt*16+r)*stride fits DS imm offset
    const u32* rzp0 = rz_lds + q*4*RZS + col;
    const u16* nnp0 = n_lds  + q*4*NSS + col;

    float hreg[16];
    #pragma unroll
    for (int i = 0; i < 16; i++) hreg[i] = 0.0f;

    #pragma unroll 1
    for (int t = 0; t < NW; t++){
        f32x4 acc[4][3];
        #pragma unroll
        for (int mt = 0; mt < 4; mt++)
            #pragma unroll
            for (int g = 0; g < 3; g++)
                #pragma unroll
                for (int i = 0; i < 4; i++) acc[mt][g][i] = (g == 2) ? bhn : 0.0f;

        if (t > 0){
            const u16* hcur = h_lds + haOff;
            // B pipelined one kc ahead of consumption (coalesced fragment loads, L2-hot)
            bf16x8 b0 = *(const bf16x8*)(wf + 0*131072);
            bf16x8 b1 = *(const bf16x8*)(wf + 1*131072);
            bf16x8 b2 = *(const bf16x8*)(wf + 2*131072);
            #pragma unroll
            for (int kc = 0; kc < 8; kc++){
                bf16x8 n0, n1, n2;
                if (kc < 7){
                    const int ko = (kc+1)*1024;
                    n0 = *(const bf16x8*)(wf + 0*131072 + ko);
                    n1 = *(const bf16x8*)(wf + 1*131072 + ko);
                    n2 = *(const bf16x8*)(wf + 2*131072 + ko);
                }
                bf16x8 a0 = *(const bf16x8*)(hcur + kc*32 +   0);
                bf16x8 a1 = *(const bf16x8*)(hcur + kc*32 + 16*HS);
                bf16x8 a2 = *(const bf16x8*)(hcur + kc*32 + 32*HS);
                bf16x8 a3 = *(const bf16x8*)(hcur + kc*32 + 48*HS);
                acc[0][0] = MFMA16(a0,b0,acc[0][0],0,0,0);
                acc[1][0] = MFMA16(a1,b0,acc[1][0],0,0,0);
                acc[2][0] = MFMA16(a2,b0,acc[2][0],0,0,0);
                acc[3][0] = MFMA16(a3,b0,acc[3][0],0,0,0);
                acc[0][1] = MFMA16(a0,b1,acc[0][1],0,0,0);
                acc[1][1] = MFMA16(a1,b1,acc[1][1],0,0,0);
                acc[2][1] = MFMA16(a2,b1,acc[2][1],0,0,0);
                acc[3][1] = MFMA16(a3,b1,acc[3][1],0,0,0);
                acc[0][2] = MFMA16(a0,b2,acc[0][2],0,0,0);
                acc[1][2] = MFMA16(a1,b2,acc[1][2],0,0,0);
                acc[2][2] = MFMA16(a2,b2,acc[2][2],0,0,0);
                acc[3][2] = MFMA16(a3,b2,acc[3][2],0,0,0);
                if (kc < 7){ b0 = n0; b1 = n1; b2 = n2; }
            }
        }
        // gate phase — window reads from LDS in 2 batches of 8 (lower live-set), hw-exp math
        const int wbase = (dir == 0) ? t : ((NW-1) - t);
        const u32* rzp = rzp0 + wbase*RZS;
        const u16* nnp = nnp0 + wbase*NSS;
        #pragma unroll
        for (int half = 0; half < 2; half++){
            u32 rz[8]; u16 nn[8];
            #pragma unroll
            for (int i = 0; i < 8; i++){
                const int ii = half*8 + i;
                const int mt = ii >> 2, r = ii & 3;
                rz[i] = rzp[(mt*16 + r)*RZS];
                nn[i] = nnp[(mt*16 + r)*NSS];
            }
            #pragma unroll
            for (int i = 0; i < 8; i++){
                const int ii = half*8 + i;
                const int mt = ii >> 2, r = ii & 3;
                const float xr = bf2f((u16)(rz[i] & 0xFFFFu));
                const float xz = bf2f((u16)(rz[i] >> 16));
                const float xn = bf2f(nn[i]);
                const float rg = sigm_hw(xr + acc[mt][0][r]);
                const float zg = sigm_hw(xz + acc[mt][1][r]);
                const float ng = tanh_hw(fmaf(rg, acc[mt][2][r], xn));
                hreg[ii] = fmaf(zg, hreg[ii] - ng, ng);
            }
        }
        if (t + 1 < NW){
            __syncthreads();                 // all h_t reads (MFMA phase) complete
            #pragma unroll
            for (int mt = 0; mt < 4; mt++)
                #pragma unroll
                for (int r = 0; r < 4; r++){
                    const int rit = mt*16 + q*4 + r;
                    h_lds[rit*HS + col] = f2bf_rh(hreg[mt*4 + r]);
                }
            __syncthreads();                 // h_{t+1} visible to all waves
        }
    }
    // epilogue: mask, store hidden (bf16), BN partial sums
    float sum = 0.0f, sumsq = 0.0f;
    #pragma unroll
    for (int mt = 0; mt < 4; mt++)
        #pragma unroll
        for (int r = 0; r < 4; r++){
            const int rit = mt*16 + q*4 + r;
            const float hm = hreg[mt*4 + r] * maskv[rit];
            hidden[(size_t)(mb*MRR + rit)*512 + dir*NH + col] = f2bf(hm);
            sum += hm; sumsq += hm*hm;
        }
    // reduce across q (lanes l15, l15+16, l15+32, l15+48 share a col)
    sum   += __shfl_xor(sum, 16);   sumsq += __shfl_xor(sumsq, 16);
    sum   += __shfl_xor(sum, 32);   sumsq += __shfl_xor(sumsq, 32);
    if (q == 0){
        atomicAdd(&bnSum[dir*NH + col], sum);
        atomicAdd(&bnSumSq[dir*NH + col], sumsq);
    }
}

// ---------------- BN finalize ----------------
__global__ void bnfin_kernel(const float* __restrict__ bnSum, const float* __restrict__ bnSumSq,
                             const float* __restrict__ gamma, const float* __restrict__ beta,
                             float* __restrict__ bnScale, float* __restrict__ bnShift)
{
    const int c = blockIdx.x*blockDim.x + threadIdx.x;
    if (c < 512){
        const float mu  = bnSum[c]   * (1.0f/16384.0f);
        const float var = bnSumSq[c] * (1.0f/16384.0f) - mu*mu;
        const float inv = rsqrtf(var + 1e-5f);
        const float sc  = gamma[c]*inv;
        bnScale[c] = sc;
        bnShift[c] = beta[c] - mu*sc;
    }
}

// ---------------- MLP + mask + max-pool ----------------
__global__ __launch_bounds__(512, 4)
void mlp_kernel(const int* __restrict__ x, const u16* __restrict__ hidden,
                const u16* __restrict__ mlpW_p, const float* __restrict__ bnScale,
                const float* __restrict__ bnShift, const float* __restrict__ mlp_b,
                unsigned* __restrict__ pooled_u)
{
    __shared__ u16 a_lds[MRE*520];
    __shared__ float maskv[MRE];
    const int tid = threadIdx.x;
    const int mb  = blockIdx.x;     // 0..511
    if (tid < MRE) maskv[tid] = (x[mb*MRE + tid] > 0) ? 1.0f : 0.0f;
    __syncthreads();
    {
        const int row = tid >> 4, jj = tid & 15;
        const float m = maskv[row];
        const u16* src = hidden + (size_t)(mb*MRE + row)*512;
        u16* dst = a_lds + row*520;
        for (int c4 = jj; c4 < 128; c4 += 16){
            ushort4 v = ((const ushort4*)src)[c4];
            const int c = c4*4;
            float4 sc = *(const float4*)(bnScale + c);
            float4 sh = *(const float4*)(bnShift + c);
            ushort4 o;
            o.x = f2bf((bf2f(v.x)*sc.x + sh.x)*m);
            o.y = f2bf((bf2f(v.y)*sc.y + sh.y)*m);
            o.z = f2bf((bf2f(v.z)*sc.z + sh.z)*m);
            o.w = f2bf((bf2f(v.w)*sc.w + sh.w)*m);
            *(ushort4*)(dst + c) = o;
        }
    }
    __syncthreads();

    const int lane = tid & 63, wv = tid >> 6, l31 = lane & 31, q = lane >> 5;
    f32x16 acc[2];
    #pragma unroll
    for (int g = 0; g < 2; g++)
        #pragma unroll
        for (int i = 0; i < 16; i++) acc[g][i] = 0.0f;

    const u16* a0p = a_lds + l31*520 + q*8;
    // fragment-packed mlpW: coalesced base+lane*16
    const char* wm0 = (const char*)mlpW_p + (size_t)((0*8 + wv)*32)*1024 + (size_t)lane*16;
    const char* wm1 = (const char*)mlpW_p + (size_t)((1*8 + wv)*32)*1024 + (size_t)lane*16;

    #pragma unroll 4
    for (int kc = 0; kc < 32; kc++){
        bf16x8 a0 = *(const bf16x8*)(a0p + kc*16);
        bf16x8 b0 = *(const bf16x8*)(wm0 + kc*1024);
        bf16x8 b1 = *(const bf16x8*)(wm1 + kc*1024);
        acc[0] = MFMA32(a0,b0,acc[0],0,0,0);
        acc[1] = MFMA32(a0,b1,acc[1],0,0,0);
    }

    const int bidx = mb >> 4;
    #pragma unroll
    for (int nt = 0; nt < 2; nt++){
        const int colg = wv*64 + nt*32 + l31;
        const float bias = mlp_b[colg];
        float mx = -3.4e38f;
        #pragma unroll
        for (int r = 0; r < 16; r++){
            const int rit = (r&3) + 8*(r>>2) + 4*q;
            const float m = maskv[rit];
            const float v = (acc[nt][r] + bias)*m + (m - 1.0f)*65500.0f;
            mx = fmaxf(mx, v);
        }
        mx = fmaxf(mx, __shfl_xor(mx, 32));
        if (q == 0) atomicMax(&pooled_u[bidx*512 + colg], fkey(mx));
    }
}

// ---------------- final linear [32x512] @ [512x2] ----------------
__global__ void final_kernel(const unsigned* __restrict__ pooled_u,
                             const float* __restrict__ linW, const float* __restrict__ linb,
                             float* __restrict__ out)
{
    const int b = blockIdx.x;       // 32
    const int lane = threadIdx.x;   // 64
    float s0 = 0.0f, s1 = 0.0f;
    for (int c = lane; c < 512; c += 64){
        const unsigned u = pooled_u[b*512 + c];
        const unsigned bits = (u & 0x80000000u) ? (u ^ 0x80000000u) : ~u;
        const float f = __uint_as_float(bits);
        s0 += f * linW[c];
        s1 += f * linW[512 + c];
    }
    #pragma unroll
    for (int off = 32; off > 0; off >>= 1){
        s0 += __shfl_xor(s0, off);
        s1 += __shfl_xor(s1, off);
    }
    if (lane == 0){ out[2*b] = s0 + linb[0]; out[2*b + 1] = s1 + linb[1]; }
}

extern "C" void kernel_launch(void* const* d_in, const int* in_sizes, int n_in,
                              void* d_out, int out_size, void* d_ws, size_t ws_size,
                              hipStream_t stream)
{
    const int*   x     = (const int*)  d_in[0];
    const float* emb   = (const float*)d_in[5];
    const float* Wih_f = (const float*)d_in[6];
    const float* Whh_f = (const float*)d_in[7];
    const float* bih_f = (const float*)d_in[8];
    const float* bhh_f = (const float*)d_in[9];
    const float* Wih_b = (const float*)d_in[10];
    const float* Whh_b = (const float*)d_in[11];
    const float* bih_b = (const float*)d_in[12];
    const float* bhh_b = (const float*)d_in[13];
    const float* gamma = (const float*)d_in[14];
    const float* beta  = (const float*)d_in[15];
    const float* mlpW  = (const float*)d_in[16];
    const float* mlpb  = (const float*)d_in[17];
    const float* linW  = (const float*)d_in[18];
    const float* linb  = (const float*)d_in[19];
    float* out = (float*)d_out;
    char* ws = (char*)d_ws;

    u16*   WihF_p  = (u16*)  (ws + 0);           // packed, 491520 B
    u16*   WihB_p  = (u16*)  (ws + 491520);
    u16*   WhhF_p  = (u16*)  (ws + 983040);      // fragment-packed, 393216 B
    u16*   WhhB_p  = (u16*)  (ws + 1376256);
    u16*   mlpW_p  = (u16*)  (ws + 1769472);     // packed, 524288 B
    float* bnSum   = (float*)(ws + 2293760);
    float* bnSumSq = (float*)(ws + 2295808);
    float* bnScale = (float*)(ws + 2297856);
    float* bnShift = (float*)(ws + 2299904);
    unsigned* pooled_u = (unsigned*)(ws + 2301952);
    u16*   hidden  = (u16*)  (ws + 2367488);     // 16384x512 bf16, 16777216 B
    u32*   rzF     = (u32*)  (ws + 19144704);    // 16448x256 u32, 16842752 B
    u16*   nF      = (u16*)  (ws + 35987456);    // 16448x256 u16, 8421376 B
    u32*   rzB     = (u32*)  (ws + 44408832);    // 16842752 B
    u16*   nB      = (u16*)  (ws + 61251584);    // 8421376 B -> end 69672960 (66.4 MB)

    prep_kernel<<<512, 256, 0, stream>>>(Wih_f, Wih_b, Whh_f, Whh_b, mlpW,
                                         WihF_p, WihB_p, WhhF_p, WhhB_p, mlpW_p,
                                         bnSum, bnSumSq, pooled_u);
    // both directions fused: one eproj dispatch, one recur dispatch
    eproj_kernel<<<1028, 512, 0, stream>>>(x, emb, WihF_p, WihB_p,
                                           bih_f, bhh_f, bih_b, bhh_b,
                                           rzF, nF, rzB, nB);
    recur_kernel<<<512, 1024, 0, stream>>>(x, rzF, nF, rzB, nB,
                                           WhhF_p, WhhB_p, bhh_f, bhh_b,
                                           hidden, bnSum, bnSumSq);

    bnfin_kernel<<<2, 256, 0, stream>>>(bnSum, bnSumSq, gamma, beta, bnScale, bnShift);
    mlp_kernel<<<512, 512, 0, stream>>>(x, hidden, mlpW_p, bnScale, bnShift, mlpb, pooled_u);
    final_kernel<<<32, 64, 0, stream>>>(pooled_u, linW, linb, out);
}